// Round 6
// baseline (181.901 us; speedup 1.0000x reference)
//
#include <hip/hip_runtime.h>
#include <math.h>

// 8x8 DCT-II matrix, exact fp32 rounding of the float64 reference values.
static constexpr float Dm[8][8] = {
  { 0.3535533906f, 0.3535533906f, 0.3535533906f, 0.3535533906f, 0.3535533906f, 0.3535533906f, 0.3535533906f, 0.3535533906f},
  { 0.4903926402f, 0.4157348062f, 0.2777851165f, 0.0975451610f,-0.0975451610f,-0.2777851165f,-0.4157348062f,-0.4903926402f},
  { 0.4619397663f, 0.1913417162f,-0.1913417162f,-0.4619397663f,-0.4619397663f,-0.1913417162f, 0.1913417162f, 0.4619397663f},
  { 0.4157348062f,-0.0975451610f,-0.4903926402f,-0.2777851165f, 0.2777851165f, 0.4903926402f, 0.0975451610f,-0.4157348062f},
  { 0.3535533906f,-0.3535533906f,-0.3535533906f, 0.3535533906f, 0.3535533906f,-0.3535533906f,-0.3535533906f, 0.3535533906f},
  { 0.2777851165f,-0.4903926402f, 0.0975451610f, 0.4157348062f,-0.4157348062f,-0.0975451610f, 0.4903926402f,-0.2777851165f},
  { 0.1913417162f,-0.4619397663f, 0.4619397663f,-0.1913417162f,-0.1913417162f, 0.4619397663f,-0.4619397663f, 0.1913417162f},
  { 0.0975451610f,-0.2777851165f, 0.4157348062f,-0.4903926402f, 0.4903926402f,-0.4157348062f, 0.2777851165f,-0.0975451610f},
};

#define ROWS    68            // plane row stride (floats): 16B aligned, bank-balanced
#define PL_CH   (8 * ROWS)    // 544 floats per channel per wave
#define PL_WAVE (3 * PL_CH)   // 1632 floats per wave
#define SCR_BLK 68            // scratch stride per 8x8 block (16B aligned)
#define SCR_WAVE (8 * SCR_BLK)

// Wave-synchronous LDS fence: all producers/consumers are within one wave,
// so a full lgkmcnt drain replaces __syncthreads. sched_barrier stops the
// compiler hoisting dependent ops above the wait (lesson: hipcc can hoist
// past inline-asm waits).
#define WAVE_SYNC() do { \
  asm volatile("s_waitcnt lgkmcnt(0)" ::: "memory"); \
  __builtin_amdgcn_sched_barrier(0); } while (0)

__global__ __launch_bounds__(256) void jpeg_fused(
    const float* __restrict__ x,
    const float* __restrict__ qlum,
    const float* __restrict__ qchr,
    float* __restrict__ out)
{
  __shared__ __attribute__((aligned(16))) float plane[4 * PL_WAVE]; // 26112 B
  __shared__ __attribute__((aligned(16))) float scr[4 * SCR_WAVE];  //  8704 B

  const int t  = threadIdx.x;      // 0..255
  const int w  = t >> 6;           // wave 0..3
  const int l  = t & 63;           // lane
  const int wg = blockIdx.x;       // 0..4095
  const int bb = wg >> 5;          // batch 0..127
  const int br = wg & 31;          // block-row 0..31
  const int base = bb * (3 * 65536) + br * (8 * 256);

  const int colg = (w << 6) + ((l & 15) << 2); // global col of this lane's float4
  const int r0   = l >> 4;                     // row-group 0..3 (rows r0, r0+4)
  const int b8l  = l >> 3;                     // local block 0..7 (compute phases)
  const int r8   = l & 7;                      // row (A/C) or column v (B)

  float* pw = &plane[w * PL_WAVE];
  float* sw = &scr[w * SCR_WAVE];

  // ---- per-thread quant tables (v = r8 column), one-time reciprocals
  float qsl[8], rql[8], qsc[8], rqc[8];
#pragma unroll
  for (int u = 0; u < 8; ++u) {
    qsl[u] = qlum[u * 8 + r8] / 1e-5f;  rql[u] = 1.0f / qsl[u];
    qsc[u] = qchr[u * 8 + r8] / 1e-5f;  rqc[u] = 1.0f / qsc[u];
  }

  // ---- load + RGB->YCbCr (coalesced dwordx4; wave-local plane cols)
#pragma unroll
  for (int rg = 0; rg < 2; ++rg) {
    const int row = r0 + 4 * rg;
    const float* px = x + base + row * 256 + colg;
    float4 r = *(const float4*)(px);
    float4 g = *(const float4*)(px + 65536);
    float4 b = *(const float4*)(px + 131072);
    float4 y, cb, cr;
    y.x  =  0.299f*r.x + 0.587f*g.x + 0.114f*b.x;
    y.y  =  0.299f*r.y + 0.587f*g.y + 0.114f*b.y;
    y.z  =  0.299f*r.z + 0.587f*g.z + 0.114f*b.z;
    y.w  =  0.299f*r.w + 0.587f*g.w + 0.114f*b.w;
    cb.x = -0.168736f*r.x - 0.331264f*g.x + 0.5f*b.x + 128.0f;
    cb.y = -0.168736f*r.y - 0.331264f*g.y + 0.5f*b.y + 128.0f;
    cb.z = -0.168736f*r.z - 0.331264f*g.z + 0.5f*b.z + 128.0f;
    cb.w = -0.168736f*r.w - 0.331264f*g.w + 0.5f*b.w + 128.0f;
    cr.x =  0.5f*r.x - 0.418688f*g.x - 0.081312f*b.x + 128.0f;
    cr.y =  0.5f*r.y - 0.418688f*g.y - 0.081312f*b.y + 128.0f;
    cr.z =  0.5f*r.z - 0.418688f*g.z - 0.081312f*b.z + 128.0f;
    cr.w =  0.5f*r.w - 0.418688f*g.w - 0.081312f*b.w + 128.0f;
    const int pidx = row * ROWS + ((l & 15) << 2);
    *(float4*)&pw[0 * PL_CH + pidx] = y;
    *(float4*)&pw[1 * PL_CH + pidx] = cb;
    *(float4*)&pw[2 * PL_CH + pidx] = cr;
  }
  WAVE_SYNC();   // load writes -> phase-A reads (cross-lane, same wave)

  // ---- per-channel DCT -> quant/dequant -> IDCT, all wave-local
#pragma unroll
  for (int ch = 0; ch < 3; ++ch) {
    float* prow = &pw[ch * PL_CH + r8 * ROWS + 8 * b8l]; // this thread's block row
    float* scol = &sw[b8l * SCR_BLK + 8 * r8];

    // Phase A: row DCT. t1[v][r] = sum_m X[r][m] D[v][m], stored transposed.
    {
      float4 x0 = *(const float4*)&prow[0];
      float4 x1 = *(const float4*)&prow[4];
      float xr[8] = {x0.x,x0.y,x0.z,x0.w,x1.x,x1.y,x1.z,x1.w};
#pragma unroll
      for (int v = 0; v < 8; ++v) {
        float acc = xr[0] * Dm[v][0];
#pragma unroll
        for (int m = 1; m < 8; ++m) acc = fmaf(xr[m], Dm[v][m], acc);
        sw[b8l * SCR_BLK + 8 * v + r8] = acc;   // scr[b][v][r]
      }
    }
    WAVE_SYNC();   // A writes -> B reads

    // Phase B: col DCT + quant/dequant + col IDCT (thread owns column v = r8)
    {
      float4 t0 = *(const float4*)&scol[0];
      float4 t1 = *(const float4*)&scol[4];
      float tc[8] = {t0.x,t0.y,t0.z,t0.w,t1.x,t1.y,t1.z,t1.w};
      float Fv[8];
#pragma unroll
      for (int u = 0; u < 8; ++u) {
        float acc = tc[0] * Dm[u][0];
#pragma unroll
        for (int r = 1; r < 8; ++r) acc = fmaf(tc[r], Dm[u][r], acc);
        const float qu = (ch == 0) ? qsl[u] : qsc[u];
        const float ru = (ch == 0) ? rql[u] : rqc[u];
        Fv[u] = rintf(acc * ru) * qu;
      }
      // col IDCT: Z[m][v] = sum_u D[u][m] F[u][v]; write transposed scr[b][m][v]
#pragma unroll
      for (int m = 0; m < 8; ++m) {
        float acc = Fv[0] * Dm[0][m];
#pragma unroll
        for (int u = 1; u < 8; ++u) acc = fmaf(Fv[u], Dm[u][m], acc);
        sw[b8l * SCR_BLK + 8 * m + r8] = acc;   // reads above issued first; same-wave DS is in-order
      }
    }
    WAVE_SYNC();   // B writes -> C reads

    // Phase C: row IDCT. Y[r][j] = sum_v Z[r][v] D[v][j]
    {
      float4 z0 = *(const float4*)&scol[0];    // scr[b][r8][v], v=0..7
      float4 z1 = *(const float4*)&scol[4];
      float zr[8] = {z0.x,z0.y,z0.z,z0.w,z1.x,z1.y,z1.z,z1.w};
      float yj[8];
#pragma unroll
      for (int j = 0; j < 8; ++j) {
        float acc = zr[0] * Dm[0][j];
#pragma unroll
        for (int v = 1; v < 8; ++v) acc = fmaf(zr[v], Dm[v][j], acc);
        yj[j] = acc;
      }
      float4 y0 = {yj[0], yj[1], yj[2], yj[3]};
      float4 y1 = {yj[4], yj[5], yj[6], yj[7]};
      *(float4*)&prow[0] = y0;
      *(float4*)&prow[4] = y1;
    }
    // no fence needed before next channel: next A reads a different plane
    // region (written pre-fence) and scr WAR is same-wave in-order.
  }
  WAVE_SYNC();   // C plane writes -> store reads

  // ---- YCbCr -> RGB, clip, coalesced dwordx4 stores
#pragma unroll
  for (int rg = 0; rg < 2; ++rg) {
    const int row = r0 + 4 * rg;
    const int pidx = row * ROWS + ((l & 15) << 2);
    float4 y  = *(const float4*)&pw[0 * PL_CH + pidx];
    float4 cb = *(const float4*)&pw[1 * PL_CH + pidx];
    float4 cr = *(const float4*)&pw[2 * PL_CH + pidx];
    cb.x -= 128.0f; cb.y -= 128.0f; cb.z -= 128.0f; cb.w -= 128.0f;
    cr.x -= 128.0f; cr.y -= 128.0f; cr.z -= 128.0f; cr.w -= 128.0f;
    float4 rr, gg, bbv;
    rr.x = fmaf(1.402f, cr.x, y.x);  rr.y = fmaf(1.402f, cr.y, y.y);
    rr.z = fmaf(1.402f, cr.z, y.z);  rr.w = fmaf(1.402f, cr.w, y.w);
    gg.x = y.x - 0.344136f*cb.x - 0.714136f*cr.x;
    gg.y = y.y - 0.344136f*cb.y - 0.714136f*cr.y;
    gg.z = y.z - 0.344136f*cb.z - 0.714136f*cr.z;
    gg.w = y.w - 0.344136f*cb.w - 0.714136f*cr.w;
    bbv.x = fmaf(1.722f, cb.x, y.x); bbv.y = fmaf(1.722f, cb.y, y.y);
    bbv.z = fmaf(1.722f, cb.z, y.z); bbv.w = fmaf(1.722f, cb.w, y.w);
    rr.x = fminf(fmaxf(rr.x, 0.0f), 255.0f);  rr.y = fminf(fmaxf(rr.y, 0.0f), 255.0f);
    rr.z = fminf(fmaxf(rr.z, 0.0f), 255.0f);  rr.w = fminf(fmaxf(rr.w, 0.0f), 255.0f);
    gg.x = fminf(fmaxf(gg.x, 0.0f), 255.0f);  gg.y = fminf(fmaxf(gg.y, 0.0f), 255.0f);
    gg.z = fminf(fmaxf(gg.z, 0.0f), 255.0f);  gg.w = fminf(fmaxf(gg.w, 0.0f), 255.0f);
    bbv.x = fminf(fmaxf(bbv.x, 0.0f), 255.0f); bbv.y = fminf(fmaxf(bbv.y, 0.0f), 255.0f);
    bbv.z = fminf(fmaxf(bbv.z, 0.0f), 255.0f); bbv.w = fminf(fmaxf(bbv.w, 0.0f), 255.0f);
    float* po = out + base + row * 256 + colg;
    *(float4*)(po)          = rr;
    *(float4*)(po + 65536)  = gg;
    *(float4*)(po + 131072) = bbv;
  }
}

extern "C" void kernel_launch(void* const* d_in, const int* in_sizes, int n_in,
                              void* d_out, int out_size, void* d_ws, size_t ws_size,
                              hipStream_t stream) {
  (void)in_sizes; (void)n_in; (void)out_size; (void)d_ws; (void)ws_size;
  const float* x    = (const float*)d_in[0];
  const float* qlum = (const float*)d_in[1];
  const float* qchr = (const float*)d_in[2];
  float* out = (float*)d_out;
  jpeg_fused<<<dim3(4096), dim3(256), 0, stream>>>(x, qlum, qchr, out);
}

// Round 7
// 179.882 us; speedup vs baseline: 1.0112x; 1.0112x over previous
//
#include <hip/hip_runtime.h>
#include <math.h>

// 8x8 DCT-II matrix, exact fp32 rounding of the float64 reference values.
static constexpr float Dm[8][8] = {
  { 0.3535533906f, 0.3535533906f, 0.3535533906f, 0.3535533906f, 0.3535533906f, 0.3535533906f, 0.3535533906f, 0.3535533906f},
  { 0.4903926402f, 0.4157348062f, 0.2777851165f, 0.0975451610f,-0.0975451610f,-0.2777851165f,-0.4157348062f,-0.4903926402f},
  { 0.4619397663f, 0.1913417162f,-0.1913417162f,-0.4619397663f,-0.4619397663f,-0.1913417162f, 0.1913417162f, 0.4619397663f},
  { 0.4157348062f,-0.0975451610f,-0.4903926402f,-0.2777851165f, 0.2777851165f, 0.4903926402f, 0.0975451610f,-0.4157348062f},
  { 0.3535533906f,-0.3535533906f,-0.3535533906f, 0.3535533906f, 0.3535533906f,-0.3535533906f,-0.3535533906f, 0.3535533906f},
  { 0.2777851165f,-0.4903926402f, 0.0975451610f, 0.4157348062f,-0.4157348062f,-0.0975451610f, 0.4903926402f,-0.2777851165f},
  { 0.1913417162f,-0.4619397663f, 0.4619397663f,-0.1913417162f,-0.1913417162f, 0.4619397663f,-0.4619397663f, 0.1913417162f},
  { 0.0975451610f,-0.2777851165f, 0.4157348062f,-0.4903926402f, 0.4903926402f,-0.4157348062f, 0.2777851165f,-0.0975451610f},
};

#define SCR_BLK 68                 // floats per 8x8 block (64 + 4 pad; 16B-aligned, banks spread)
#define SCR_CH  (8 * SCR_BLK)     // 544 floats per channel per wave
#define SCR_WAVE (3 * SCR_CH)     // 1632 floats per wave

// Wave-synchronous LDS fence (all LDS producer/consumer pairs are same-wave).
#define WAVE_SYNC() do { \
  asm volatile("s_waitcnt lgkmcnt(0)" ::: "memory"); \
  __builtin_amdgcn_sched_barrier(0); } while (0)

__global__ __launch_bounds__(256) void jpeg_fused(
    const float* __restrict__ x,
    const float* __restrict__ qlum,
    const float* __restrict__ qchr,
    float* __restrict__ out)
{
  __shared__ __attribute__((aligned(16))) float scr[4 * SCR_WAVE]; // 26112 B total

  const int t  = threadIdx.x;      // 0..255
  const int w  = t >> 6;           // wave 0..3
  const int l  = t & 63;           // lane
  const int wg = blockIdx.x;       // 0..4095
  const int bb = wg >> 5;          // batch 0..127
  const int br = wg & 31;          // block-row 0..31

  const int blk = l >> 3;          // lane's block within the wave's 8-block group
  const int r8  = l & 7;           // row owned (load/A/C/store); column owned (B)
  const int goff = bb * (3 * 65536) + br * (8 * 256) + r8 * 256 + (w * 8 + blk) * 8;

  float* sw = &scr[w * SCR_WAVE];
  float* sb0 = &sw[0 * SCR_CH + blk * SCR_BLK];
  float* sb1 = &sw[1 * SCR_CH + blk * SCR_BLK];
  float* sb2 = &sw[2 * SCR_CH + blk * SCR_BLK];

  // ---- global loads: lane's 8-float row of its block, all 3 channels (6 dwordx4)
  const float* px = x + goff;
  float4 R0 = *(const float4*)(px);
  float4 R1 = *(const float4*)(px + 4);
  float4 G0 = *(const float4*)(px + 65536);
  float4 G1 = *(const float4*)(px + 65540);
  float4 B0 = *(const float4*)(px + 131072);
  float4 B1 = *(const float4*)(px + 131076);

  // ---- per-lane quant tables for column v = r8 (match reference: q / S, then recip)
  float qsl[8], rql[8], qsc[8], rqc[8];
#pragma unroll
  for (int u = 0; u < 8; ++u) {
    qsl[u] = qlum[u * 8 + r8] / 1e-5f;  rql[u] = 1.0f / qsl[u];
    qsc[u] = qchr[u * 8 + r8] / 1e-5f;  rqc[u] = 1.0f / qsc[u];
  }

  // ---- RGB -> YCbCr rows in registers
  float rr[8] = {R0.x,R0.y,R0.z,R0.w,R1.x,R1.y,R1.z,R1.w};
  float gr[8] = {G0.x,G0.y,G0.z,G0.w,G1.x,G1.y,G1.z,G1.w};
  float brw[8] = {B0.x,B0.y,B0.z,B0.w,B1.x,B1.y,B1.z,B1.w};
  float yr[8], cbr[8], crr[8];
#pragma unroll
  for (int n = 0; n < 8; ++n) {
    yr[n]  =  0.299f   * rr[n] + 0.587f    * gr[n] + 0.114f    * brw[n];
    cbr[n] = -0.168736f* rr[n] - 0.331264f * gr[n] + 0.5f      * brw[n] + 128.0f;
    crr[n] =  0.5f     * rr[n] - 0.418688f * gr[n] - 0.081312f * brw[n] + 128.0f;
  }

  // ---- Phase A (x3 channels): row DCT, write transposed scr[blk][8v + r8]
#define PHASE_A(rowarr, sb) do { \
  _Pragma("unroll") \
  for (int v = 0; v < 8; ++v) { \
    float acc = rowarr[0] * Dm[v][0]; \
    _Pragma("unroll") \
    for (int m = 1; m < 8; ++m) acc = fmaf(rowarr[m], Dm[v][m], acc); \
    (sb)[8 * v + r8] = acc; \
  } } while (0)
  PHASE_A(yr,  sb0);
  PHASE_A(cbr, sb1);
  PHASE_A(crr, sb2);
#undef PHASE_A
  WAVE_SYNC();   // A writes -> B reads (cross-lane within 8-lane group, same wave)

  // ---- Phase B (x3): col DCT + quant/dequant + col IDCT; lane owns column v=r8
#define PHASE_B(sb, qs, rq) do { \
  float4 t0 = *(const float4*)&(sb)[8 * r8]; \
  float4 t1 = *(const float4*)&(sb)[8 * r8 + 4]; \
  float tc[8] = {t0.x,t0.y,t0.z,t0.w,t1.x,t1.y,t1.z,t1.w}; \
  float Fv[8]; \
  _Pragma("unroll") \
  for (int u = 0; u < 8; ++u) { \
    float acc = tc[0] * Dm[u][0]; \
    _Pragma("unroll") \
    for (int r = 1; r < 8; ++r) acc = fmaf(tc[r], Dm[u][r], acc); \
    Fv[u] = rintf(acc * (rq)[u]) * (qs)[u]; \
  } \
  _Pragma("unroll") \
  for (int m = 0; m < 8; ++m) { \
    float acc = Fv[0] * Dm[0][m]; \
    _Pragma("unroll") \
    for (int u = 1; u < 8; ++u) acc = fmaf(Fv[u], Dm[u][m], acc); \
    (sb)[8 * m + r8] = acc;  /* wave DS ops in-order: reads above precede these writes */ \
  } } while (0)
  PHASE_B(sb0, qsl, rql);
  PHASE_B(sb1, qsc, rqc);
  PHASE_B(sb2, qsc, rqc);
#undef PHASE_B
  WAVE_SYNC();   // B writes -> C reads

  // ---- Phase C (x3): row IDCT back into registers; lane owns row r8 again
#define PHASE_C(sb, outarr) do { \
  float4 z0 = *(const float4*)&(sb)[8 * r8]; \
  float4 z1 = *(const float4*)&(sb)[8 * r8 + 4]; \
  float zr[8] = {z0.x,z0.y,z0.z,z0.w,z1.x,z1.y,z1.z,z1.w}; \
  _Pragma("unroll") \
  for (int j = 0; j < 8; ++j) { \
    float acc = zr[0] * Dm[0][j]; \
    _Pragma("unroll") \
    for (int v = 1; v < 8; ++v) acc = fmaf(zr[v], Dm[v][j], acc); \
    outarr[j] = acc; \
  } } while (0)
  PHASE_C(sb0, yr);
  PHASE_C(sb1, cbr);
  PHASE_C(sb2, crr);
#undef PHASE_C

  // ---- YCbCr -> RGB, clip, store lane's row (6 dwordx4)
  float ro[8], go[8], bo[8];
#pragma unroll
  for (int j = 0; j < 8; ++j) {
    float y  = yr[j];
    float cb = cbr[j] - 128.0f;
    float cr = crr[j] - 128.0f;
    float r2 = fmaf(1.402f, cr, y);
    float g2 = y - 0.344136f * cb - 0.714136f * cr;
    float b2 = fmaf(1.722f, cb, y);
    ro[j] = fminf(fmaxf(r2, 0.0f), 255.0f);
    go[j] = fminf(fmaxf(g2, 0.0f), 255.0f);
    bo[j] = fminf(fmaxf(b2, 0.0f), 255.0f);
  }
  float* po = out + goff;
  *(float4*)(po)           = (float4){ro[0], ro[1], ro[2], ro[3]};
  *(float4*)(po + 4)       = (float4){ro[4], ro[5], ro[6], ro[7]};
  *(float4*)(po + 65536)   = (float4){go[0], go[1], go[2], go[3]};
  *(float4*)(po + 65540)   = (float4){go[4], go[5], go[6], go[7]};
  *(float4*)(po + 131072)  = (float4){bo[0], bo[1], bo[2], bo[3]};
  *(float4*)(po + 131076)  = (float4){bo[4], bo[5], bo[6], bo[7]};
}

extern "C" void kernel_launch(void* const* d_in, const int* in_sizes, int n_in,
                              void* d_out, int out_size, void* d_ws, size_t ws_size,
                              hipStream_t stream) {
  (void)in_sizes; (void)n_in; (void)out_size; (void)d_ws; (void)ws_size;
  const float* x    = (const float*)d_in[0];
  const float* qlum = (const float*)d_in[1];
  const float* qchr = (const float*)d_in[2];
  float* out = (float*)d_out;
  // 128 batches * 32 block-rows = 4096 workgroups of 256 threads.
  jpeg_fused<<<dim3(4096), dim3(256), 0, stream>>>(x, qlum, qchr, out);
}